// Round 1
// baseline (1435.605 us; speedup 1.0000x reference)
//
#include <hip/hip_runtime.h>
#include <math.h>

// Problem constants
#define NB 2
#define NC 256
#define NG 16
#define CG 16
#define HH 192
#define WW 192
#define HO 190
#define PP 144

// LDS tile geometry for gram kernel
#define PADR 196              // floats per row (192 data + 4 pad), 16B aligned
#define CSTR 788              // floats per channel (4 rows * 196 + 4 skew), %32==20 -> banks spread

// ---------------------------------------------------------------------------
// Kernel 1: partial Gram matrices, f32 chunk accumulation -> f64 atomic add.
// grid = (32 bg, 19 L-chunks), block = 256 (16x16 channel pairs).
// Each thread owns channel pair (ty, tx) and all 81 (shift_p, shift_q) pairs.
// ---------------------------------------------------------------------------
__global__ __launch_bounds__(256, 2) void gram_kernel(const float* __restrict__ x,
                                                      double* __restrict__ gram)
{
    __shared__ float tile[CG * CSTR];   // 50432 B
    const int bg = blockIdx.x;          // 0..31  (b*16+g)
    const int b = bg >> 4, g = bg & 15;
    const int tid = threadIdx.x;
    const int ty = tid >> 4, tx = tid & 15;

    float acc[81];
#pragma unroll
    for (int s = 0; s < 81; ++s) acc[s] = 0.f;

    const float* xg = x + ((size_t)(b * NC + g * CG)) * (HH * WW);

    const int band0 = blockIdx.y * 5;   // 19 * 5 = 95 bands of 2 l-rows = 190
    for (int band = band0; band < band0 + 5; ++band) {
        const int ho0 = band * 2;       // x-rows ho0..ho0+3 needed (<=191)
        __syncthreads();
        // cooperative load: 16 ch x 4 rows x 192 cols = 3072 float4 / 256 thr
#pragma unroll
        for (int k = 0; k < 12; ++k) {
            int idx = tid + 256 * k;
            int ch = idx / 192;
            int rem = idx - ch * 192;
            int r = rem / 48;
            int c4 = (rem - r * 48) * 4;
            float4 v = *(const float4*)(xg + ((size_t)ch * HH + (ho0 + r)) * WW + c4);
            *(float4*)(&tile[ch * CSTR + r * PADR + c4]) = v;
        }
        __syncthreads();

        const float* ta = &tile[ty * CSTR];
        const float* tb = &tile[tx * CSTR];
#pragma unroll
        for (int lr = 0; lr < 2; ++lr) {
            // 47 full quads cover wo = 0..187
            for (int wq = 0; wq < 47; ++wq) {
                const int wo = wq * 4;
                float A[3][8], Bm[3][8];
#pragma unroll
                for (int i = 0; i < 3; ++i) {
                    *(float4*)&A[i][0]  = *(const float4*)(ta + (lr + i) * PADR + wo);
                    *(float4*)&A[i][4]  = *(const float4*)(ta + (lr + i) * PADR + wo + 4);
                    *(float4*)&Bm[i][0] = *(const float4*)(tb + (lr + i) * PADR + wo);
                    *(float4*)&Bm[i][4] = *(const float4*)(tb + (lr + i) * PADR + wo + 4);
                }
#pragma unroll
                for (int i = 0; i < 3; ++i)
#pragma unroll
                for (int j = 0; j < 3; ++j)
#pragma unroll
                for (int i2 = 0; i2 < 3; ++i2)
#pragma unroll
                for (int j2 = 0; j2 < 3; ++j2) {
                    const int s = (i * 3 + j) * 9 + i2 * 3 + j2;
#pragma unroll
                    for (int k = 0; k < 4; ++k)
                        acc[s] = fmaf(A[i][j + k], Bm[i2][j2 + k], acc[s]);
                }
            }
            // tail wo = 188,189
#pragma unroll
            for (int wt = 0; wt < 2; ++wt) {
                const int wo = 188 + wt;
                float a[9], bb[9];
#pragma unroll
                for (int i = 0; i < 3; ++i)
#pragma unroll
                for (int j = 0; j < 3; ++j) {
                    a[i * 3 + j]  = ta[(lr + i) * PADR + wo + j];
                    bb[i * 3 + j] = tb[(lr + i) * PADR + wo + j];
                }
#pragma unroll
                for (int s = 0; s < 9; ++s)
#pragma unroll
                for (int t = 0; t < 9; ++t)
                    acc[s * 9 + t] = fmaf(a[s], bb[t], acc[s * 9 + t]);
            }
        }
    }

    double* gp = gram + (size_t)bg * (PP * PP);
#pragma unroll
    for (int s = 0; s < 9; ++s)
#pragma unroll
    for (int t = 0; t < 9; ++t) {
        const int p = ty * 9 + s, q = tx * 9 + t;
        atomicAdd(&gp[p * PP + q], (double)acc[s * 9 + t]);
    }
}

// ---------------------------------------------------------------------------
// Kernel 2: per-group argmin (f64 d2, first-min tiebreak), bincount over both
// batches, stable top-3 (smallest index on count ties, matching lax.top_k).
// grid = 16 groups, block = 320.
// ---------------------------------------------------------------------------
__global__ __launch_bounds__(320) void topk_kernel(const double* __restrict__ gram,
                                                   float* __restrict__ pf,
                                                   int* __restrict__ pi)
{
    const int g = blockIdx.x;
    __shared__ double sdiag[2][PP];
    __shared__ int counts[PP];
    const int tid = threadIdx.x;
    if (tid < PP) counts[tid] = 0;
    if (tid < 2 * PP) {
        const int b = tid / PP, p = tid % PP;
        const double* gb = gram + (size_t)(b * 16 + g) * (PP * PP);
        sdiag[b][p] = gb[p * PP + p];
    }
    __syncthreads();
    if (tid < 2 * PP) {
        const int b = tid / PP, p = tid % PP;
        const double* row = gram + ((size_t)(b * 16 + g) * PP + p) * PP;
        const double sp = sdiag[b][p];
        double best = 1e300;
        int bi = 0;
        for (int q = 0; q < PP; ++q) {
            if (q == p) continue;
            const double d2 = sp + sdiag[b][q] - 2.0 * row[q];
            if (d2 < best) { best = d2; bi = q; }   // strict < : first occurrence
        }
        atomicAdd(&counts[bi], 1);
    }
    __syncthreads();
    if (tid == 0) {
        int sel[3], cv[3];
        for (int o = 0; o < 3; ++o) {
            int bc = -1, bp = 0;
            for (int p = 0; p < PP; ++p) {
                bool taken = false;
                for (int u = 0; u < o; ++u) if (sel[u] == p) taken = true;
                if (!taken && counts[p] > bc) { bc = counts[p]; bp = p; } // > keeps lowest idx
            }
            sel[o] = bp; cv[o] = bc;
        }
        const int tot = cv[0] + cv[1] + cv[2];
        for (int o = 0; o < 3; ++o) {
            pf[g * 4 + o] = (float)cv[o];
            pi[g * 4 + o] = sel[o];
        }
        pf[g * 4 + 3] = (float)tot;
    }
}

// ---------------------------------------------------------------------------
// Kernel 3: fused "scale by top rows -> floor -> fold" stencil.
// out[b,c,h,w] = sum_{o<3} sum_{i,j valid} floor(((x*R_o[h-i,w-j])*cf_o)/total)
// Exact IEEE op order matches the reference; results are small integers.
// One thread = 4 consecutive w (float4 aligned).
// ---------------------------------------------------------------------------
__global__ __launch_bounds__(256) void out_kernel(const float* __restrict__ x,
                                                  const float* __restrict__ pf,
                                                  const int* __restrict__ pi,
                                                  float* __restrict__ out)
{
    const int gid = blockIdx.x * 256 + threadIdx.x;
    const int w4 = gid % 48;
    int t = gid / 48;
    const int h = t % HH; t /= HH;
    const int ch = t % NC;
    const int b = t / NC;
    const int g = ch >> 4;
    const int w0 = w4 * 4;

    const size_t base = ((size_t)(b * NC + ch)) * (HH * WW);
    const float4 xv4 = *(const float4*)(x + base + (size_t)h * WW + w0);
    const float xs[4] = {xv4.x, xv4.y, xv4.z, xv4.w};
    float acc[4] = {0.f, 0.f, 0.f, 0.f};
    const float total = pf[g * 4 + 3];

#pragma unroll
    for (int o = 0; o < 3; ++o) {
        const int p = pi[g * 4 + o];
        const float cf = pf[g * 4 + o];
        const int co = p / 9;
        const int kk = p - co * 9;
        const int io = kk / 3, jo = kk - (kk / 3) * 3;
        const float* Rb = x + ((size_t)(b * NC + g * CG + co)) * (HH * WW);
#pragma unroll
        for (int i = 0; i < 3; ++i) {
            const int ho = h - i;
            const bool rowok = (ho >= 0) && (ho < HO);
            int hr = ho + io;
            hr = hr < 0 ? 0 : (hr > HH - 1 ? HH - 1 : hr);
            const float* row = Rb + (size_t)hr * WW;
            float rv[6];
#pragma unroll
            for (int u = 0; u < 6; ++u) {
                int col = w0 - 2 + jo + u;
                col = col < 0 ? 0 : (col > WW - 1 ? WW - 1 : col);
                rv[u] = row[col];
            }
#pragma unroll
            for (int j = 0; j < 3; ++j)
#pragma unroll
            for (int q = 0; q < 4; ++q) {
                const int wo = w0 + q - j;
                const bool ok = rowok && (wo >= 0) && (wo < HO);
                const float r = rv[q - j + 2];
                const float v = floorf(__fdiv_rn(__fmul_rn(__fmul_rn(xs[q], r), cf), total));
                acc[q] += ok ? v : 0.f;
            }
        }
    }
    float4 ov = make_float4(acc[0], acc[1], acc[2], acc[3]);
    *(float4*)(out + base + (size_t)h * WW + w0) = ov;
}

// ---------------------------------------------------------------------------
extern "C" void kernel_launch(void* const* d_in, const int* in_sizes, int n_in,
                              void* d_out, int out_size, void* d_ws, size_t ws_size,
                              hipStream_t stream)
{
    const float* x = (const float*)d_in[0];
    float* out = (float*)d_out;

    double* gram = (double*)d_ws;
    const size_t gram_bytes = (size_t)32 * PP * PP * sizeof(double); // 5,308,416 B
    float* pf = (float*)((char*)d_ws + gram_bytes);
    int* pi = (int*)((char*)d_ws + gram_bytes + 256);

    hipMemsetAsync(d_ws, 0, gram_bytes, stream);

    dim3 gg(32, 19);
    gram_kernel<<<gg, 256, 0, stream>>>(x, gram);
    topk_kernel<<<16, 320, 0, stream>>>(gram, pf, pi);
    out_kernel<<<18432, 256, 0, stream>>>(x, pf, pi, out);
}

// Round 2
// 606.335 us; speedup vs baseline: 2.3677x; 2.3677x over previous
//
#include <hip/hip_runtime.h>
#include <math.h>

// Problem constants
#define NB 2
#define NC 256
#define CG 16
#define HH 192
#define WW 192
#define HO 190
#define PP 144

// ---------------------------------------------------------------------------
// Kernel 1 (rewritten): correlation-decomposed Gram.
// gram[p][q], p=(c1,i1,j1), q=(c2,i2,j2) = corr(c1,c2, di=i2-i1, dj=j2-j1)
// summed over window [i1,i1+189]x[j1,j1+189]. Compute 25 offsets per channel
// pair; recover all 81 window sums via edge-row/edge-column corrections.
// Zero-padding cancels exactly (every padded term entering the full sum is
// subtracted back out; invalid (i1,j1) per offset are never emitted).
//
// Block = 192 threads (thread-per-column v). Each block: one bg, one c2,
// two c1 (2*idx, 2*idx+1) sharing the x2 LDS band. Grid = 32 * 72.
// Main loop: register-rolled 5x5 window, 5 LDS b32 + 2 global per 50 FMA.
// ---------------------------------------------------------------------------
__global__ __launch_bounds__(192) void gram_kernel(const float* __restrict__ x,
                                                   double* __restrict__ gram)
{
    __shared__ float smem[44 * 196];          // band buffer; later edge(12*196)+red
    float* const band_s = smem;
    float* const edge_s = smem;               // 12*196 = 2352
    float* const red_s  = smem + 12 * 196;    // 192*26 = 4992 (total 7344 <= 8624)

    const int v = threadIdx.x;                // column 0..191
    int r = blockIdx.x;
    const int bg = r / 72; r -= bg * 72;
    int c2 = 0;
    while (r >= (c2 + 2) / 2) { r -= (c2 + 2) / 2; ++c2; }
    const int c1a = 2 * r;
    int c1b = 2 * r + 1;
    const bool bval = (c1b <= c2);
    if (!bval) c1b = c2;
    const int b = bg >> 4, g = bg & 15;

    const float* __restrict__ xa  = x + ((size_t)(b * NC + g * CG + c1a)) * (HH * WW);
    const float* __restrict__ xb  = x + ((size_t)(b * NC + g * CG + c1b)) * (HH * WW);
    const float* __restrict__ x2g = x + ((size_t)(b * NC + g * CG + c2 )) * (HH * WW);

    float mid[2][25];
#pragma unroll
    for (int o = 0; o < 25; ++o) { mid[0][o] = 0.f; mid[1][o] = 0.f; }

    float win[5][5];

    // one u-step: absolute u = u0 + S (S % 5 == S5), window rows u-2..u+2 in
    // slots (S5+k)%5 (k=di+2); new row u+2 -> slot (S5+4)%5.
#define USTEP(S5, S)                                                          \
    {                                                                         \
        const int u = u0 + (S);                                               \
        const int lrow = (S) + 4;                                             \
        _Pragma("unroll")                                                     \
        for (int dj = 0; dj < 5; ++dj)                                        \
            win[((S5) + 4) % 5][dj] = band_s[lrow * 196 + v + dj];            \
        const float a1 = xa[u * WW + v];                                      \
        const float b1 = xb[u * WW + v];                                      \
        _Pragma("unroll")                                                     \
        for (int k = 0; k < 5; ++k) {                                         \
            _Pragma("unroll")                                                 \
            for (int dj = 0; dj < 5; ++dj) {                                  \
                const float xv = win[((S5) + k) % 5][dj];                     \
                mid[0][k * 5 + dj] = fmaf(a1, xv, mid[0][k * 5 + dj]);        \
                mid[1][k * 5 + dj] = fmaf(b1, xv, mid[1][k * 5 + dj]);        \
            }                                                                 \
        }                                                                     \
    }

    // main loop u in [2,189], bands of 40 steps (last 28); rows staged with
    // 2-col zero pad each side (row layout: [0,1]=pad, [2..193]=cols, [194,195]=pad)
    for (int band_i = 0; band_i < 5; ++band_i) {
        const int u0 = 2 + band_i * 40;
        const int usteps = (band_i == 4) ? 28 : 40;
        const int row0 = u0 - 2;                    // row0 % 5 == 0
        const int nrows = usteps + 4;
        __syncthreads();
        for (int rr = 0; rr < nrows; ++rr) {
            band_s[rr * 196 + v + 2] = x2g[(row0 + rr) * WW + v];
            if (v < 2)    band_s[rr * 196 + v] = 0.f;
            if (v >= 190) band_s[rr * 196 + v + 4] = 0.f;
        }
        __syncthreads();
        // prologue: rows u0-2 .. u0+1 -> slots 0..3
#pragma unroll
        for (int k = 0; k < 4; ++k)
#pragma unroll
        for (int dj = 0; dj < 5; ++dj)
            win[k][dj] = band_s[k * 196 + v + dj];

        for (int sb = 0; sb + 5 <= usteps; sb += 5) {
            USTEP(0, sb + 0) USTEP(1, sb + 1) USTEP(2, sb + 2)
            USTEP(3, sb + 3) USTEP(4, sb + 4)
        }
        if (usteps == 28) {            // tail s = 25,26,27 (phases 0,1,2)
            USTEP(0, 25) USTEP(1, 26) USTEP(2, 27)
        }
    }
#undef USTEP

    // stage edge buffer: buf i<6 -> abs row i-2 (OOB rows zero), i>=6 -> 188+(i-6)
    __syncthreads();
    for (int i = 0; i < 12; ++i) {
        const int ar = (i < 6) ? (i - 2) : (188 + i - 6);
        const float val = (ar >= 0 && ar <= 191) ? x2g[ar * WW + v] : 0.f;
        edge_s[i * 196 + v + 2] = val;
        if (v < 2)    edge_s[i * 196 + v] = 0.f;
        if (v >= 190) edge_s[i * 196 + v + 4] = 0.f;
    }
    __syncthreads();

    double* const gp = gram + (size_t)bg * (PP * PP);

    // chunks: i1=0 edge rows (0,1); i1=1 (1,190); i1=2 (190,191)
#pragma unroll
    for (int i1 = 0; i1 < 3; ++i1) {
        const int ra = (i1 == 0) ? 0 : ((i1 == 1) ? 1 : 190);
        const int rb = (i1 == 0) ? 1 : ((i1 == 1) ? 190 : 191);
#pragma unroll
        for (int c = 0; c < 2; ++c) {
            const float* __restrict__ xc = (c == 0) ? xa : xb;
            const float xra = xc[ra * WW + v];
            const float xrb = xc[rb * WW + v];
            // cw(v) = mid + P[ra] + P[rb], write to red
#pragma unroll
            for (int k = 0; k < 5; ++k) {
                const int bufa = (ra < 2) ? (ra + (k - 2) + 2) : (ra + (k - 2) - 182);
                const int bufb = (rb < 2) ? (rb + (k - 2) + 2) : (rb + (k - 2) - 182);
#pragma unroll
                for (int dj = 0; dj < 5; ++dj) {
                    float cw = mid[c][k * 5 + dj];
                    cw = fmaf(xra, edge_s[bufa * 196 + v + dj], cw);
                    cw = fmaf(xrb, edge_s[bufb * 196 + v + dj], cw);
                    red_s[v * 26 + k * 5 + dj] = cw;
                }
            }
            __syncthreads();
            float e0 = 0.f, e1 = 0.f, e190 = 0.f, e191 = 0.f;
            if (v < 25) {
                e0   = red_s[0 * 26 + v];
                e1   = red_s[1 * 26 + v];
                e190 = red_s[190 * 26 + v];
                e191 = red_s[191 * 26 + v];
            }
            __syncthreads();
            // tree reduce over columns: 192 -> 96 -> ... -> 3
#pragma unroll
            for (int s = 96; s >= 3; s >>= 1) {
                for (int idx = v; idx < s * 25; idx += 192) {
                    const int vv = idx / 25, o = idx - vv * 25;
                    red_s[vv * 26 + o] += red_s[(vv + s) * 26 + o];
                }
                __syncthreads();
            }
            if (v < 25 && (c == 0 || bval)) {
                const int di = v / 5 - 2, dj = v - (v / 5) * 5 - 2;
                const int i2 = i1 + di;
                if (i2 >= 0 && i2 <= 2) {
                    const float S = red_s[0 * 26 + v] + red_s[1 * 26 + v] + red_s[2 * 26 + v];
                    const int c1 = (c == 0) ? c1a : c1b;
#pragma unroll
                    for (int j1 = 0; j1 < 3; ++j1) {
                        const int j2 = j1 + dj;
                        if (j2 < 0 || j2 > 2) continue;
                        const float W = S - ((j1 == 0) ? (e190 + e191)
                                          : (j1 == 1) ? (e0 + e191)
                                                      : (e0 + e1));
                        const int p = c1 * 9 + i1 * 3 + j1;
                        const int q = c2 * 9 + i2 * 3 + j2;
                        gp[p * PP + q] = (double)W;
                        if (c1 != c2) gp[q * PP + p] = (double)W;
                    }
                }
            }
            __syncthreads();   // red reused by next (i1,c)
        }
    }
}

// ---------------------------------------------------------------------------
// Kernel 2: per-group argmin (f64 d2, first-min tiebreak), bincount over both
// batches, stable top-3 (smallest index on count ties, matching lax.top_k).
// ---------------------------------------------------------------------------
__global__ __launch_bounds__(320) void topk_kernel(const double* __restrict__ gram,
                                                   float* __restrict__ pf,
                                                   int* __restrict__ pi)
{
    const int g = blockIdx.x;
    __shared__ double sdiag[2][PP];
    __shared__ int counts[PP];
    const int tid = threadIdx.x;
    if (tid < PP) counts[tid] = 0;
    if (tid < 2 * PP) {
        const int b = tid / PP, p = tid % PP;
        const double* gb = gram + (size_t)(b * 16 + g) * (PP * PP);
        sdiag[b][p] = gb[p * PP + p];
    }
    __syncthreads();
    if (tid < 2 * PP) {
        const int b = tid / PP, p = tid % PP;
        const double* row = gram + ((size_t)(b * 16 + g) * PP + p) * PP;
        const double sp = sdiag[b][p];
        double best = 1e300;
        int bi = 0;
        for (int q = 0; q < PP; ++q) {
            if (q == p) continue;
            const double d2 = sp + sdiag[b][q] - 2.0 * row[q];
            if (d2 < best) { best = d2; bi = q; }   // strict < : first occurrence
        }
        atomicAdd(&counts[bi], 1);
    }
    __syncthreads();
    if (tid == 0) {
        int sel[3], cv[3];
        for (int o = 0; o < 3; ++o) {
            int bc = -1, bp = 0;
            for (int p = 0; p < PP; ++p) {
                bool taken = false;
                for (int u = 0; u < o; ++u) if (sel[u] == p) taken = true;
                if (!taken && counts[p] > bc) { bc = counts[p]; bp = p; } // > keeps lowest idx
            }
            sel[o] = bp; cv[o] = bc;
        }
        const int tot = cv[0] + cv[1] + cv[2];
        for (int o = 0; o < 3; ++o) {
            pf[g * 4 + o] = (float)cv[o];
            pi[g * 4 + o] = sel[o];
        }
        pf[g * 4 + 3] = (float)tot;
    }
}

// ---------------------------------------------------------------------------
// Kernel 3: fused "scale by top rows -> floor -> fold" stencil (bit-exact
// IEEE op order vs reference). One thread = 4 consecutive w.
// ---------------------------------------------------------------------------
__global__ __launch_bounds__(256) void out_kernel(const float* __restrict__ x,
                                                  const float* __restrict__ pf,
                                                  const int* __restrict__ pi,
                                                  float* __restrict__ out)
{
    const int gid = blockIdx.x * 256 + threadIdx.x;
    const int w4 = gid % 48;
    int t = gid / 48;
    const int h = t % HH; t /= HH;
    const int ch = t % NC;
    const int b = t / NC;
    const int g = ch >> 4;
    const int w0 = w4 * 4;

    const size_t base = ((size_t)(b * NC + ch)) * (HH * WW);
    const float4 xv4 = *(const float4*)(x + base + (size_t)h * WW + w0);
    const float xs[4] = {xv4.x, xv4.y, xv4.z, xv4.w};
    float acc[4] = {0.f, 0.f, 0.f, 0.f};
    const float total = pf[g * 4 + 3];

#pragma unroll
    for (int o = 0; o < 3; ++o) {
        const int p = pi[g * 4 + o];
        const float cf = pf[g * 4 + o];
        const int co = p / 9;
        const int kk = p - co * 9;
        const int io = kk / 3, jo = kk - (kk / 3) * 3;
        const float* Rb = x + ((size_t)(b * NC + g * CG + co)) * (HH * WW);
#pragma unroll
        for (int i = 0; i < 3; ++i) {
            const int ho = h - i;
            const bool rowok = (ho >= 0) && (ho < HO);
            int hr = ho + io;
            hr = hr < 0 ? 0 : (hr > HH - 1 ? HH - 1 : hr);
            const float* row = Rb + (size_t)hr * WW;
            float rv[6];
#pragma unroll
            for (int u = 0; u < 6; ++u) {
                int col = w0 - 2 + jo + u;
                col = col < 0 ? 0 : (col > WW - 1 ? WW - 1 : col);
                rv[u] = row[col];
            }
#pragma unroll
            for (int j = 0; j < 3; ++j)
#pragma unroll
            for (int q = 0; q < 4; ++q) {
                const int wo = w0 + q - j;
                const bool ok = rowok && (wo >= 0) && (wo < HO);
                const float r2 = rv[q - j + 2];
                const float vv = floorf(__fdiv_rn(__fmul_rn(__fmul_rn(xs[q], r2), cf), total));
                acc[q] += ok ? vv : 0.f;
            }
        }
    }
    float4 ov = make_float4(acc[0], acc[1], acc[2], acc[3]);
    *(float4*)(out + base + (size_t)h * WW + w0) = ov;
}

// ---------------------------------------------------------------------------
extern "C" void kernel_launch(void* const* d_in, const int* in_sizes, int n_in,
                              void* d_out, int out_size, void* d_ws, size_t ws_size,
                              hipStream_t stream)
{
    const float* x = (const float*)d_in[0];
    float* out = (float*)d_out;

    double* gram = (double*)d_ws;
    const size_t gram_bytes = (size_t)32 * PP * PP * sizeof(double); // 5,308,416 B
    float* pf = (float*)((char*)d_ws + gram_bytes);
    int* pi = (int*)((char*)d_ws + gram_bytes + 256);

    gram_kernel<<<32 * 72, 192, 0, stream>>>(x, gram);
    topk_kernel<<<16, 320, 0, stream>>>(gram, pf, pi);
    out_kernel<<<18432, 256, 0, stream>>>(x, pf, pi, out);
}